// Round 2
// baseline (767.315 us; speedup 1.0000x reference)
//
#include <hip/hip_runtime.h>

// GraphSAGE 2-layer, fp32.
// N=40000 nodes, E=640000 edges, 128 -> 512 (relu) -> 256.
// Restructuring: layer1 aggregates x (128-wide) BEFORE gemm; layer2 does
// hl = h@W2l FIRST then aggregates 256-wide (aggregation commutes with linear).
// Aggregation via CSR (deg atomics -> single-block scan -> fill) + gather.
// NOTE: harness passes integer inputs as int32 (NOT int64, despite jnp.int64
// in the reference) — edge_index is const int*, laid out [2][E] flat.

#define N_NODES 40000
#define N_EDGES 640000
#define F_IN 128
#define F_HID 512
#define F_OUT 256

__global__ void deg_kernel(const int* __restrict__ ei, int* __restrict__ deg) {
  int e = blockIdx.x * blockDim.x + threadIdx.x;
  if (e < N_EDGES) {
    int d = ei[N_EDGES + e];  // row 1 = dst
    atomicAdd(&deg[d], 1);
  }
}

// Single-block exclusive scan over deg -> rowptr, cursor. 40 chunks of 1024.
__global__ __launch_bounds__(1024) void scan_kernel(const int* __restrict__ deg,
                                                    int* __restrict__ rowptr,
                                                    int* __restrict__ cursor) {
  __shared__ int buf[2][1024];
  __shared__ int carry_s;
  int tid = threadIdx.x;
  if (tid == 0) carry_s = 0;
  __syncthreads();
  const int nch = (N_NODES + 1023) / 1024;
  for (int c = 0; c < nch; ++c) {
    int i = c * 1024 + tid;
    int v = (i < N_NODES) ? deg[i] : 0;
    buf[0][tid] = v;
    __syncthreads();
    int cur = 0;
    #pragma unroll
    for (int off = 1; off < 1024; off <<= 1) {
      int val = buf[cur][tid];
      if (tid >= off) val += buf[cur][tid - off];
      buf[cur ^ 1][tid] = val;
      __syncthreads();
      cur ^= 1;
    }
    int inc = buf[cur][tid];       // inclusive scan of this chunk
    int base = carry_s;
    if (i < N_NODES) {
      int ex = base + inc - v;     // exclusive
      rowptr[i] = ex;
      cursor[i] = ex;
    }
    __syncthreads();               // all reads of carry_s / buf done
    if (tid == 1023) carry_s = base + inc;
    __syncthreads();
  }
  if (tid == 0) rowptr[N_NODES] = carry_s;  // == E
}

__global__ void fill_kernel(const int* __restrict__ ei, int* __restrict__ cursor,
                            int* __restrict__ col) {
  int e = blockIdx.x * blockDim.x + threadIdx.x;
  if (e < N_EDGES) {
    int d = ei[N_EDGES + e];
    int s = ei[e];
    int pos = atomicAdd(&cursor[d], 1);
    col[pos] = s;
  }
}

// One block per node, F threads (= feature width). Mean-aggregate gathered rows.
template <int F>
__global__ void agg_mean_kernel(const float* __restrict__ X, float* __restrict__ Y,
                                const int* __restrict__ rowptr,
                                const int* __restrict__ colidx) {
  __shared__ int cols[F];
  int n = blockIdx.x;
  int f = threadIdx.x;
  int s = rowptr[n], e = rowptr[n + 1];
  float sum = 0.f;
  for (int base = s; base < e; base += F) {
    int cnt = min(F, e - base);
    __syncthreads();
    if (f < cnt) cols[f] = colidx[base + f];
    __syncthreads();
    for (int j = 0; j < cnt; ++j) sum += X[(size_t)cols[j] * F + f];
  }
  float d = (float)(e - s);
  Y[(size_t)n * F + f] = sum / fmaxf(d, 1.0f);
}

// Register-tiled fp32 GEMM: C[M,N] = (sum over pairs) A_p[M,K] @ W_p[K,N] (+bias)(+C)(relu).
// BM=BN=64, BK=32, 256 threads, 4x4 micro-tile per thread.
template <bool RELU, bool ACC, bool HASBIAS, bool TWOPAIR>
__global__ __launch_bounds__(256) void gemm64(
    const float* __restrict__ A0, const float* __restrict__ W0,
    const float* __restrict__ A1, const float* __restrict__ W1,
    const float* __restrict__ bias, float* __restrict__ C,
    int M, int N, int K) {
  const int BM = 64, BN = 64, BK = 32;
  __shared__ float As[BK][BM + 4];  // +4 pad keeps float4 reads 16B-aligned, breaks conflicts
  __shared__ float Bs[BK][BN];
  const int tid = threadIdx.x;
  const int tx = tid & 15, ty = tid >> 4;
  const int bm = blockIdx.x * BM;
  const int bn = blockIdx.y * BN;
  float acc[4][4] = {};
  const int npair = TWOPAIR ? 2 : 1;
  for (int p = 0; p < npair; ++p) {
    const float* __restrict__ A = p ? A1 : A0;
    const float* __restrict__ W = p ? W1 : W0;
    for (int kb = 0; kb < K; kb += BK) {
      // A tile: 64 rows x 32 k, float4 loads, transpose into As[k][m]
      #pragma unroll
      for (int q = 0; q < 2; ++q) {
        int idx = tid + q * 256;       // 0..511 float4s
        int row = idx >> 3;            // 8 float4 per row
        int c4 = (idx & 7) << 2;
        float4 v = *(const float4*)&A[(size_t)(bm + row) * K + kb + c4];
        As[c4 + 0][row] = v.x;
        As[c4 + 1][row] = v.y;
        As[c4 + 2][row] = v.z;
        As[c4 + 3][row] = v.w;
      }
      // W tile: 32 k x 64 n, float4, natural layout
      #pragma unroll
      for (int q = 0; q < 2; ++q) {
        int idx = tid + q * 256;
        int row = idx >> 4;            // 16 float4 per row
        int c4 = (idx & 15) << 2;
        *(float4*)&Bs[row][c4] = *(const float4*)&W[(size_t)(kb + row) * N + bn + c4];
      }
      __syncthreads();
      #pragma unroll
      for (int k = 0; k < BK; ++k) {
        float4 af = *(const float4*)&As[k][ty << 2];
        float4 bf = *(const float4*)&Bs[k][tx << 2];
        float av[4] = {af.x, af.y, af.z, af.w};
        float bv[4] = {bf.x, bf.y, bf.z, bf.w};
        #pragma unroll
        for (int r = 0; r < 4; ++r)
          #pragma unroll
          for (int cc = 0; cc < 4; ++cc)
            acc[r][cc] += av[r] * bv[cc];
      }
      __syncthreads();
    }
  }
  float bvv[4] = {0.f, 0.f, 0.f, 0.f};
  if (HASBIAS) {
    float4 t = *(const float4*)&bias[bn + (tx << 2)];
    bvv[0] = t.x; bvv[1] = t.y; bvv[2] = t.z; bvv[3] = t.w;
  }
  #pragma unroll
  for (int r = 0; r < 4; ++r) {
    size_t off = (size_t)(bm + (ty << 2) + r) * N + bn + (tx << 2);
    float4 o;
    o.x = acc[r][0] + bvv[0];
    o.y = acc[r][1] + bvv[1];
    o.z = acc[r][2] + bvv[2];
    o.w = acc[r][3] + bvv[3];
    if (ACC) {
      float4 prev = *(const float4*)&C[off];
      o.x += prev.x; o.y += prev.y; o.z += prev.z; o.w += prev.w;
    }
    if (RELU) {
      o.x = fmaxf(o.x, 0.f); o.y = fmaxf(o.y, 0.f);
      o.z = fmaxf(o.z, 0.f); o.w = fmaxf(o.w, 0.f);
    }
    *(float4*)&C[off] = o;
  }
}

extern "C" void kernel_launch(void* const* d_in, const int* in_sizes, int n_in,
                              void* d_out, int out_size, void* d_ws, size_t ws_size,
                              hipStream_t stream) {
  const float* x = (const float*)d_in[0];
  const int* ei = (const int*)d_in[1];      // int32 per harness contract, [2][E]
  const float* W1l = (const float*)d_in[2];
  const float* b1 = (const float*)d_in[3];
  const float* W1r = (const float*)d_in[4];
  const float* W2l = (const float*)d_in[5];
  const float* b2 = (const float*)d_in[6];
  const float* W2r = (const float*)d_in[7];
  float* out = (float*)d_out;

  char* ws = (char*)d_ws;
  size_t off = 0;
  auto alloc = [&](size_t bytes) {
    void* p = ws + off;
    off = (off + bytes + 255) & ~(size_t)255;
    return p;
  };
  int* deg = (int*)alloc((size_t)N_NODES * 4);
  int* rowptr = (int*)alloc((size_t)(N_NODES + 1) * 4);
  int* cursor = (int*)alloc((size_t)N_NODES * 4);
  int* col = (int*)alloc((size_t)N_EDGES * 4);
  float* aggx = (float*)alloc((size_t)N_NODES * F_IN * 4);   // mean-aggregated x
  float* h = (float*)alloc((size_t)N_NODES * F_HID * 4);     // layer-1 output
  float* hl = (float*)alloc((size_t)N_NODES * F_OUT * 4);    // h @ W2l

  hipMemsetAsync(deg, 0, (size_t)N_NODES * 4, stream);
  deg_kernel<<<(N_EDGES + 255) / 256, 256, 0, stream>>>(ei, deg);
  scan_kernel<<<1, 1024, 0, stream>>>(deg, rowptr, cursor);
  fill_kernel<<<(N_EDGES + 255) / 256, 256, 0, stream>>>(ei, cursor, col);

  // Layer 1: aggx = mean-agg(x); h = relu(aggx@W1l + x@W1r + b1)
  agg_mean_kernel<F_IN><<<N_NODES, F_IN, 0, stream>>>(x, aggx, rowptr, col);
  gemm64<true, false, true, true><<<dim3(N_NODES / 64, F_HID / 64), 256, 0, stream>>>(
      aggx, W1l, x, W1r, b1, h, N_NODES, F_HID, F_IN);

  // Layer 2: hl = h@W2l; out = mean-agg(hl); out += h@W2r + b2
  gemm64<false, false, false, false><<<dim3(N_NODES / 64, F_OUT / 64), 256, 0, stream>>>(
      h, W2l, nullptr, nullptr, nullptr, hl, N_NODES, F_OUT, F_HID);
  agg_mean_kernel<F_OUT><<<N_NODES, F_OUT, 0, stream>>>(hl, out, rowptr, col);
  gemm64<false, true, true, false><<<dim3(N_NODES / 64, F_OUT / 64), 256, 0, stream>>>(
      h, W2r, nullptr, nullptr, b2, out, N_NODES, F_OUT, F_HID);
}

// Round 3
// 446.896 us; speedup vs baseline: 1.7170x; 1.7170x over previous
//
#include <hip/hip_runtime.h>

// GraphSAGE 2-layer. N=40000, E=640000, 128 -> 512 (relu) -> 256.
// Round 3: bf16 MFMA GEMMs (16x16x32, 128x128 tile, global_load_lds staging),
// GEMM2+GEMM3 fused via concatenated [W2l|W2r]^T (N=512), agg2 adds the
// h@W2r+b2 term in its epilogue. fp32 accumulate throughout; absmax budget
// 0.102 (bf16-floor threshold).

#define N_NODES 40000
#define N_EDGES 640000
#define F_IN 128
#define F_HID 512
#define F_OUT 256

typedef unsigned short ushort_t;
typedef __attribute__((ext_vector_type(8))) short bf16x8;
typedef __attribute__((ext_vector_type(4))) float floatx4;

__device__ __forceinline__ ushort_t f2bf(float f) {
  union { float f; unsigned int u; } x; x.f = f;
  unsigned int r = (x.u + 0x7FFFu + ((x.u >> 16) & 1u)) >> 16;  // RNE
  return (ushort_t)r;
}
__device__ __forceinline__ float bf2f(ushort_t u) {
  union { unsigned int u; float f; } x; x.u = ((unsigned int)u) << 16;
  return x.f;
}

// ---------------- CSR build ----------------
__global__ void deg_kernel(const int* __restrict__ ei, int* __restrict__ deg) {
  int e = blockIdx.x * blockDim.x + threadIdx.x;
  if (e < N_EDGES) atomicAdd(&deg[ei[N_EDGES + e]], 1);
}

// One block, 1024 threads, 40 elems/thread + one block-wide scan.
__global__ __launch_bounds__(1024) void scan_kernel(const int* __restrict__ deg,
                                                    int* __restrict__ rowptr,
                                                    int* __restrict__ cursor) {
  const int PER = 40;  // 1024*40 = 40960 >= N_NODES+1
  __shared__ int buf[2][1024];
  int tid = threadIdx.x;
  int base = tid * PER;
  int loc[PER];
  int sum = 0;
  #pragma unroll
  for (int i = 0; i < PER; ++i) {
    int idx = base + i;
    int v = (idx < N_NODES) ? deg[idx] : 0;
    loc[i] = sum;  // exclusive within this thread's run
    sum += v;
  }
  buf[0][tid] = sum;
  __syncthreads();
  int cur = 0;
  #pragma unroll
  for (int off = 1; off < 1024; off <<= 1) {
    int val = buf[cur][tid];
    if (tid >= off) val += buf[cur][tid - off];
    buf[cur ^ 1][tid] = val;
    __syncthreads();
    cur ^= 1;
  }
  int excl = buf[cur][tid] - sum;  // exclusive prefix of this thread's run
  #pragma unroll
  for (int i = 0; i < PER; ++i) {
    int idx = base + i;
    if (idx < N_NODES) {
      int v = excl + loc[i];
      rowptr[idx] = v;
      cursor[idx] = v;
    } else if (idx == N_NODES) {
      rowptr[N_NODES] = excl + loc[i];  // == E
    }
  }
}

__global__ void fill_kernel(const int* __restrict__ ei, int* __restrict__ cursor,
                            int* __restrict__ col) {
  int e = blockIdx.x * blockDim.x + threadIdx.x;
  if (e < N_EDGES) {
    int d = ei[N_EDGES + e];
    int s = ei[e];
    int pos = atomicAdd(&cursor[d], 1);
    col[pos] = s;
  }
}

// ---------------- conversions ----------------
__global__ void cvt_x_kernel(const float* __restrict__ x, ushort_t* __restrict__ xb) {
  int i = blockIdx.x * blockDim.x + threadIdx.x;  // per float4
  const int n4 = (N_NODES * F_IN) / 4;
  if (i < n4) {
    float4 v = ((const float4*)x)[i];
    ushort4 o;
    o.x = f2bf(v.x); o.y = f2bf(v.y); o.z = f2bf(v.z); o.w = f2bf(v.w);
    ((ushort4*)xb)[i] = o;
  }
}

// Wt[(rowoff+n)*ldt + k] = bf16(W[k*N + n])   (transpose + convert)
__global__ void wt_kernel(const float* __restrict__ W, ushort_t* __restrict__ Wt,
                          int K, int N, int rowoff, int ldt) {
  int i = blockIdx.x * blockDim.x + threadIdx.x;  // i = n*K + k (coalesced write)
  if (i < K * N) {
    int n = i / K, k = i - n * K;
    Wt[(size_t)(rowoff + n) * ldt + k] = f2bf(W[(size_t)k * N + n]);
  }
}

__global__ void biascat_kernel(const float* __restrict__ b2, float* __restrict__ bc) {
  int i = threadIdx.x + blockIdx.x * blockDim.x;
  if (i < 512) bc[i] = (i < 256) ? 0.f : b2[i - 256];
}

// ---------------- aggregation ----------------
// Layer 1: bf16 in, bf16 out, F=128. One block (128 thr) per node.
__global__ void agg1_kernel(const ushort_t* __restrict__ Xb, ushort_t* __restrict__ Yb,
                            const int* __restrict__ rowptr, const int* __restrict__ colidx) {
  __shared__ int cols[128];
  int n = blockIdx.x, f = threadIdx.x;
  int s = rowptr[n], e = rowptr[n + 1];
  float sum = 0.f;
  for (int base = s; base < e; base += 128) {
    int cnt = min(128, e - base);
    __syncthreads();
    if (f < cnt) cols[f] = colidx[base + f];
    __syncthreads();
    for (int j = 0; j < cnt; ++j) sum += bf2f(Xb[(size_t)cols[j] * F_IN + f]);
  }
  Yb[(size_t)n * F_IN + f] = f2bf(sum / fmaxf((float)(e - s), 1.f));
}

// Layer 2: gather hcat[:,0:256] (row stride 512), add hcat[n][256+f] (= h@W2r + b2).
__global__ void agg2_kernel(const float* __restrict__ H, float* __restrict__ out,
                            const int* __restrict__ rowptr, const int* __restrict__ colidx) {
  __shared__ int cols[256];
  int n = blockIdx.x, f = threadIdx.x;
  int s = rowptr[n], e = rowptr[n + 1];
  float sum = 0.f;
  for (int base = s; base < e; base += 256) {
    int cnt = min(256, e - base);
    __syncthreads();
    if (f < cnt) cols[f] = colidx[base + f];
    __syncthreads();
    for (int j = 0; j < cnt; ++j) sum += H[(size_t)cols[j] * 512 + f];
  }
  out[(size_t)n * F_OUT + f] =
      sum / fmaxf((float)(e - s), 1.f) + H[(size_t)n * 512 + 256 + f];
}

// ---------------- bf16 MFMA GEMM ----------------
// C[M,N] = (sum p) A_p[M,K] @ W_p[K,N] (+bias)(relu), A bf16 row-major,
// W given TRANSPOSED bf16: Wt[n][k], row stride K.
// 128x128 tile, 4 waves (2x2), each wave 4x4 frags of 16x16x32.
template <bool TWOPAIR, bool RELU, bool BIAS, bool OUT_BF16>
__global__ __launch_bounds__(256) void gemm_mfma(
    const ushort_t* __restrict__ A0, const ushort_t* __restrict__ A1,
    const ushort_t* __restrict__ W0t, const ushort_t* __restrict__ W1t,
    const float* __restrict__ bias, float* __restrict__ Cf,
    ushort_t* __restrict__ Cb, int M, int N, int K) {
  const int BM = 128, BN = 128, BK = 32;
  __shared__ ushort_t At[BM * BK];  // [128 m][32 k]
  __shared__ ushort_t Bt[BN * BK];  // [128 n][32 k]
  const int tid = threadIdx.x;
  const int wave = tid >> 6, lane = tid & 63;
  const int lm = lane & 15, qk = lane >> 4;
  const int wm = wave & 1, wn = wave >> 1;
  const int bm = blockIdx.x * BM, bn = blockIdx.y * BN;
  floatx4 acc[4][4] = {};
  const int npair = TWOPAIR ? 2 : 1;
  for (int p = 0; p < npair; ++p) {
    const ushort_t* __restrict__ A = p ? A1 : A0;
    const ushort_t* __restrict__ Wt = p ? W1t : W0t;
    for (int kb = 0; kb < K; kb += BK) {
      // Stage 8KB A-tile + 8KB B-tile via global_load_lds width=16.
      // Chunk c (0..511): row = c>>2, kchunk = c&3. LDS dst = base + lane*16.
      #pragma unroll
      for (int pass = 0; pass < 2; ++pass) {
        int c = pass * 256 + wave * 64 + lane;
        int row = c >> 2, kc = c & 3;
        int ar = min(bm + row, M - 1);  // clamp tail rows (stores are guarded)
        const ushort_t* ga = A + (size_t)ar * K + kb + kc * 8;
        const ushort_t* gb = Wt + (size_t)(bn + row) * K + kb + kc * 8;
        ushort_t* la = At + (size_t)(pass * 256 + wave * 64) * 8;
        ushort_t* lb = Bt + (size_t)(pass * 256 + wave * 64) * 8;
        __builtin_amdgcn_global_load_lds(
            (const __attribute__((address_space(1))) void*)ga,
            (__attribute__((address_space(3))) void*)la, 16, 0, 0);
        __builtin_amdgcn_global_load_lds(
            (const __attribute__((address_space(1))) void*)gb,
            (__attribute__((address_space(3))) void*)lb, 16, 0, 0);
      }
      __syncthreads();
      bf16x8 av[4], bv[4];
      #pragma unroll
      for (int mi = 0; mi < 4; ++mi)
        av[mi] = *(const bf16x8*)(At + (wm * 64 + mi * 16 + lm) * BK + qk * 8);
      #pragma unroll
      for (int ni = 0; ni < 4; ++ni)
        bv[ni] = *(const bf16x8*)(Bt + (wn * 64 + ni * 16 + lm) * BK + qk * 8);
      #pragma unroll
      for (int mi = 0; mi < 4; ++mi)
        #pragma unroll
        for (int ni = 0; ni < 4; ++ni)
          acc[mi][ni] = __builtin_amdgcn_mfma_f32_16x16x32_bf16(
              av[mi], bv[ni], acc[mi][ni], 0, 0, 0);
      __syncthreads();
    }
  }
  // Epilogue. C/D frag: col = lane&15, row = (lane>>4)*4 + reg.
  const int rowbase = bm + wm * 64 + qk * 4;
  const int colbase = bn + wn * 64 + lm;
  #pragma unroll
  for (int ni = 0; ni < 4; ++ni) {
    int colg = colbase + ni * 16;
    float bval = BIAS ? bias[colg] : 0.f;
    #pragma unroll
    for (int mi = 0; mi < 4; ++mi) {
      #pragma unroll
      for (int r = 0; r < 4; ++r) {
        int rowg = rowbase + mi * 16 + r;
        if (rowg < M) {
          float v = acc[mi][ni][r] + bval;
          if (RELU) v = fmaxf(v, 0.f);
          if (OUT_BF16) Cb[(size_t)rowg * N + colg] = f2bf(v);
          else Cf[(size_t)rowg * N + colg] = v;
        }
      }
    }
  }
}

extern "C" void kernel_launch(void* const* d_in, const int* in_sizes, int n_in,
                              void* d_out, int out_size, void* d_ws, size_t ws_size,
                              hipStream_t stream) {
  const float* x = (const float*)d_in[0];
  const int* ei = (const int*)d_in[1];  // int32 per harness, [2][E]
  const float* W1l = (const float*)d_in[2];
  const float* b1 = (const float*)d_in[3];
  const float* W1r = (const float*)d_in[4];
  const float* W2l = (const float*)d_in[5];
  const float* b2 = (const float*)d_in[6];
  const float* W2r = (const float*)d_in[7];
  float* out = (float*)d_out;

  char* ws = (char*)d_ws;
  size_t off = 0;
  auto alloc = [&](size_t bytes) {
    void* p = ws + off;
    off = (off + bytes + 255) & ~(size_t)255;
    return p;
  };
  int* deg = (int*)alloc((size_t)N_NODES * 4);
  int* rowptr = (int*)alloc((size_t)(N_NODES + 1) * 4);
  int* cursor = (int*)alloc((size_t)N_NODES * 4);
  int* col = (int*)alloc((size_t)N_EDGES * 4);
  ushort_t* x_bf = (ushort_t*)alloc((size_t)N_NODES * F_IN * 2);
  ushort_t* aggx_bf = (ushort_t*)alloc((size_t)N_NODES * F_IN * 2);
  ushort_t* h_bf = (ushort_t*)alloc((size_t)N_NODES * F_HID * 2);
  float* hcat = (float*)alloc((size_t)N_NODES * 512 * 4);  // [h@W2l | h@W2r+b2]
  ushort_t* W1lt = (ushort_t*)alloc((size_t)F_HID * F_IN * 2);   // [512][128]
  ushort_t* W1rt = (ushort_t*)alloc((size_t)F_HID * F_IN * 2);   // [512][128]
  ushort_t* Wcatt = (ushort_t*)alloc((size_t)512 * F_HID * 2);   // [512][512]
  float* biascat = (float*)alloc(512 * 4);

  // CSR build
  hipMemsetAsync(deg, 0, (size_t)N_NODES * 4, stream);
  deg_kernel<<<(N_EDGES + 255) / 256, 256, 0, stream>>>(ei, deg);
  scan_kernel<<<1, 1024, 0, stream>>>(deg, rowptr, cursor);
  fill_kernel<<<(N_EDGES + 255) / 256, 256, 0, stream>>>(ei, cursor, col);

  // Conversions (independent of CSR)
  cvt_x_kernel<<<(N_NODES * F_IN / 4 + 255) / 256, 256, 0, stream>>>(x, x_bf);
  wt_kernel<<<(F_IN * F_HID + 255) / 256, 256, 0, stream>>>(W1l, W1lt, F_IN, F_HID, 0, F_IN);
  wt_kernel<<<(F_IN * F_HID + 255) / 256, 256, 0, stream>>>(W1r, W1rt, F_IN, F_HID, 0, F_IN);
  wt_kernel<<<(F_HID * F_OUT + 255) / 256, 256, 0, stream>>>(W2l, Wcatt, F_HID, F_OUT, 0, F_HID);
  wt_kernel<<<(F_HID * F_OUT + 255) / 256, 256, 0, stream>>>(W2r, Wcatt, F_HID, F_OUT, 256, F_HID);
  biascat_kernel<<<2, 256, 0, stream>>>(b2, biascat);

  // Layer 1: aggx_bf = mean-agg(x_bf); h_bf = relu(aggx@W1l + x@W1r + b1)
  agg1_kernel<<<N_NODES, 128, 0, stream>>>(x_bf, aggx_bf, rowptr, col);
  gemm_mfma<true, true, true, true>
      <<<dim3((N_NODES + 127) / 128, F_HID / 128), 256, 0, stream>>>(
          aggx_bf, x_bf, W1lt, W1rt, b1, nullptr, h_bf, N_NODES, F_HID, F_IN);

  // Layer 2 fused: hcat = h_bf @ [W2l|W2r] + [0|b2]
  gemm_mfma<false, false, true, false>
      <<<dim3((N_NODES + 127) / 128, 512 / 128), 256, 0, stream>>>(
          h_bf, nullptr, Wcatt, nullptr, biascat, hcat, nullptr, N_NODES, 512, F_HID);
  // out = mean-agg(hcat[:,0:256]) + hcat[:,256:512]
  agg2_kernel<<<N_NODES, 256, 0, stream>>>(hcat, out, rowptr, col);
}

// Round 4
// 396.801 us; speedup vs baseline: 1.9338x; 1.1262x over previous
//
#include <hip/hip_runtime.h>

// GraphSAGE 2-layer. N=40000, E=640000, 128 -> 512 (relu) -> 256.
// Round 4: layer-2 gather path in bf16 — gemm2 epilogue splits output into
// compact hl_bf (bf16, gathered by agg2, half the bytes of fp32) and hr
// (fp32, read sequentially once). agg kernels vectorized to uint (2x bf16)
// loads. absmax budget 0.102 (bf16-floor threshold); round-3 was 0.031.

#define N_NODES 40000
#define N_EDGES 640000
#define F_IN 128
#define F_HID 512
#define F_OUT 256

typedef unsigned short ushort_t;
typedef __attribute__((ext_vector_type(8))) short bf16x8;
typedef __attribute__((ext_vector_type(4))) float floatx4;

__device__ __forceinline__ ushort_t f2bf(float f) {
  union { float f; unsigned int u; } x; x.f = f;
  unsigned int r = (x.u + 0x7FFFu + ((x.u >> 16) & 1u)) >> 16;  // RNE
  return (ushort_t)r;
}
__device__ __forceinline__ float bf2f(ushort_t u) {
  union { unsigned int u; float f; } x; x.u = ((unsigned int)u) << 16;
  return x.f;
}

// ---------------- CSR build ----------------
__global__ void deg_kernel(const int* __restrict__ ei, int* __restrict__ deg) {
  int e = blockIdx.x * blockDim.x + threadIdx.x;
  if (e < N_EDGES) atomicAdd(&deg[ei[N_EDGES + e]], 1);
}

// One block, 1024 threads, 40 elems/thread + one block-wide scan.
__global__ __launch_bounds__(1024) void scan_kernel(const int* __restrict__ deg,
                                                    int* __restrict__ rowptr,
                                                    int* __restrict__ cursor) {
  const int PER = 40;  // 1024*40 = 40960 >= N_NODES+1
  __shared__ int buf[2][1024];
  int tid = threadIdx.x;
  int base = tid * PER;
  int loc[PER];
  int sum = 0;
  #pragma unroll
  for (int i = 0; i < PER; ++i) {
    int idx = base + i;
    int v = (idx < N_NODES) ? deg[idx] : 0;
    loc[i] = sum;  // exclusive within this thread's run
    sum += v;
  }
  buf[0][tid] = sum;
  __syncthreads();
  int cur = 0;
  #pragma unroll
  for (int off = 1; off < 1024; off <<= 1) {
    int val = buf[cur][tid];
    if (tid >= off) val += buf[cur][tid - off];
    buf[cur ^ 1][tid] = val;
    __syncthreads();
    cur ^= 1;
  }
  int excl = buf[cur][tid] - sum;  // exclusive prefix of this thread's run
  #pragma unroll
  for (int i = 0; i < PER; ++i) {
    int idx = base + i;
    if (idx < N_NODES) {
      int v = excl + loc[i];
      rowptr[idx] = v;
      cursor[idx] = v;
    } else if (idx == N_NODES) {
      rowptr[N_NODES] = excl + loc[i];  // == E
    }
  }
}

__global__ void fill_kernel(const int* __restrict__ ei, int* __restrict__ cursor,
                            int* __restrict__ col) {
  int e = blockIdx.x * blockDim.x + threadIdx.x;
  if (e < N_EDGES) {
    int d = ei[N_EDGES + e];
    int s = ei[e];
    int pos = atomicAdd(&cursor[d], 1);
    col[pos] = s;
  }
}

// ---------------- conversions ----------------
__global__ void cvt_x_kernel(const float* __restrict__ x, ushort_t* __restrict__ xb) {
  int i = blockIdx.x * blockDim.x + threadIdx.x;  // per float4
  const int n4 = (N_NODES * F_IN) / 4;
  if (i < n4) {
    float4 v = ((const float4*)x)[i];
    ushort4 o;
    o.x = f2bf(v.x); o.y = f2bf(v.y); o.z = f2bf(v.z); o.w = f2bf(v.w);
    ((ushort4*)xb)[i] = o;
  }
}

// Wt[(rowoff+n)*ldt + k] = bf16(W[k*N + n])   (transpose + convert)
__global__ void wt_kernel(const float* __restrict__ W, ushort_t* __restrict__ Wt,
                          int K, int N, int rowoff, int ldt) {
  int i = blockIdx.x * blockDim.x + threadIdx.x;  // i = n*K + k (coalesced write)
  if (i < K * N) {
    int n = i / K, k = i - n * K;
    Wt[(size_t)(rowoff + n) * ldt + k] = f2bf(W[(size_t)k * N + n]);
  }
}

__global__ void biascat_kernel(const float* __restrict__ b2, float* __restrict__ bc) {
  int i = threadIdx.x + blockIdx.x * blockDim.x;
  if (i < 512) bc[i] = (i < 256) ? 0.f : b2[i - 256];
}

// ---------------- aggregation ----------------
// Layer 1: bf16 in/out, F=128. One wave (64 thr) per node; each lane owns
// 2 adjacent cols via uint loads.
__global__ void agg1_kernel(const ushort_t* __restrict__ Xb, ushort_t* __restrict__ Yb,
                            const int* __restrict__ rowptr, const int* __restrict__ colidx) {
  __shared__ int cols[64];
  int n = blockIdx.x, f = threadIdx.x;
  int s = rowptr[n], e = rowptr[n + 1];
  float s0 = 0.f, s1 = 0.f;
  for (int base = s; base < e; base += 64) {
    int cnt = min(64, e - base);
    __syncthreads();
    if (f < cnt) cols[f] = colidx[base + f];
    __syncthreads();
    for (int j = 0; j < cnt; ++j) {
      unsigned int v = *(const unsigned int*)(Xb + (size_t)cols[j] * F_IN + 2 * f);
      s0 += bf2f((ushort_t)(v & 0xffffu));
      s1 += bf2f((ushort_t)(v >> 16));
    }
  }
  float inv = 1.f / fmaxf((float)(e - s), 1.f);
  unsigned int o = (unsigned int)f2bf(s0 * inv) | ((unsigned int)f2bf(s1 * inv) << 16);
  *(unsigned int*)(Yb + (size_t)n * F_IN + 2 * f) = o;
}

// Layer 2: gather compact bf16 hl rows (512B each), add fp32 hr[n], write fp32 out.
// 128 threads per node; each lane owns 2 adjacent cols.
__global__ void agg2_kernel(const ushort_t* __restrict__ hl, const float* __restrict__ hr,
                            float* __restrict__ out,
                            const int* __restrict__ rowptr, const int* __restrict__ colidx) {
  __shared__ int cols[128];
  int n = blockIdx.x, f = threadIdx.x;
  int s = rowptr[n], e = rowptr[n + 1];
  float s0 = 0.f, s1 = 0.f;
  for (int base = s; base < e; base += 128) {
    int cnt = min(128, e - base);
    __syncthreads();
    if (f < cnt) cols[f] = colidx[base + f];
    __syncthreads();
    for (int j = 0; j < cnt; ++j) {
      unsigned int v = *(const unsigned int*)(hl + (size_t)cols[j] * F_OUT + 2 * f);
      s0 += bf2f((ushort_t)(v & 0xffffu));
      s1 += bf2f((ushort_t)(v >> 16));
    }
  }
  float inv = 1.f / fmaxf((float)(e - s), 1.f);
  float2 hrv = *(const float2*)(hr + (size_t)n * F_OUT + 2 * f);
  float2 o;
  o.x = s0 * inv + hrv.x;
  o.y = s1 * inv + hrv.y;
  *(float2*)(out + (size_t)n * F_OUT + 2 * f) = o;
}

// ---------------- bf16 MFMA GEMM ----------------
// C[M,N] = (sum p) A_p[M,K] @ W_p[K,N] (+bias)(relu), A bf16 row-major,
// W given TRANSPOSED bf16: Wt[n][k], row stride K.
// 128x128 tile, 4 waves (2x2), each wave 4x4 frags of 16x16x32.
// SPLITOUT (N==512 only): cols 0:256 -> Cb bf16 [M][256]; cols 256:512 -> Cf
// fp32 [M][256]. The split is block-uniform (tile BN=128 lies in one half).
template <bool TWOPAIR, bool RELU, bool BIAS, bool OUT_BF16, bool SPLITOUT>
__global__ __launch_bounds__(256) void gemm_mfma(
    const ushort_t* __restrict__ A0, const ushort_t* __restrict__ A1,
    const ushort_t* __restrict__ W0t, const ushort_t* __restrict__ W1t,
    const float* __restrict__ bias, float* __restrict__ Cf,
    ushort_t* __restrict__ Cb, int M, int N, int K) {
  const int BM = 128, BN = 128, BK = 32;
  __shared__ ushort_t At[BM * BK];  // [128 m][32 k]
  __shared__ ushort_t Bt[BN * BK];  // [128 n][32 k]
  const int tid = threadIdx.x;
  const int wave = tid >> 6, lane = tid & 63;
  const int lm = lane & 15, qk = lane >> 4;
  const int wm = wave & 1, wn = wave >> 1;
  const int bm = blockIdx.x * BM, bn = blockIdx.y * BN;
  floatx4 acc[4][4] = {};
  const int npair = TWOPAIR ? 2 : 1;
  for (int p = 0; p < npair; ++p) {
    const ushort_t* __restrict__ A = p ? A1 : A0;
    const ushort_t* __restrict__ Wt = p ? W1t : W0t;
    for (int kb = 0; kb < K; kb += BK) {
      // Stage 8KB A-tile + 8KB B-tile via global_load_lds width=16.
      #pragma unroll
      for (int pass = 0; pass < 2; ++pass) {
        int c = pass * 256 + wave * 64 + lane;
        int row = c >> 2, kc = c & 3;
        int ar = min(bm + row, M - 1);  // clamp tail rows (stores are guarded)
        const ushort_t* ga = A + (size_t)ar * K + kb + kc * 8;
        const ushort_t* gb = Wt + (size_t)(bn + row) * K + kb + kc * 8;
        ushort_t* la = At + (size_t)(pass * 256 + wave * 64) * 8;
        ushort_t* lb = Bt + (size_t)(pass * 256 + wave * 64) * 8;
        __builtin_amdgcn_global_load_lds(
            (const __attribute__((address_space(1))) void*)ga,
            (__attribute__((address_space(3))) void*)la, 16, 0, 0);
        __builtin_amdgcn_global_load_lds(
            (const __attribute__((address_space(1))) void*)gb,
            (__attribute__((address_space(3))) void*)lb, 16, 0, 0);
      }
      __syncthreads();
      bf16x8 av[4], bv[4];
      #pragma unroll
      for (int mi = 0; mi < 4; ++mi)
        av[mi] = *(const bf16x8*)(At + (wm * 64 + mi * 16 + lm) * BK + qk * 8);
      #pragma unroll
      for (int ni = 0; ni < 4; ++ni)
        bv[ni] = *(const bf16x8*)(Bt + (wn * 64 + ni * 16 + lm) * BK + qk * 8);
      #pragma unroll
      for (int mi = 0; mi < 4; ++mi)
        #pragma unroll
        for (int ni = 0; ni < 4; ++ni)
          acc[mi][ni] = __builtin_amdgcn_mfma_f32_16x16x32_bf16(
              av[mi], bv[ni], acc[mi][ni], 0, 0, 0);
      __syncthreads();
    }
  }
  // Epilogue. C/D frag: col = lane&15, row = (lane>>4)*4 + reg.
  const int rowbase = bm + wm * 64 + qk * 4;
  const int colbase = bn + wn * 64 + lm;
  #pragma unroll
  for (int ni = 0; ni < 4; ++ni) {
    int colg = colbase + ni * 16;
    float bval = BIAS ? bias[colg] : 0.f;
    #pragma unroll
    for (int mi = 0; mi < 4; ++mi) {
      #pragma unroll
      for (int r = 0; r < 4; ++r) {
        int rowg = rowbase + mi * 16 + r;
        if (rowg < M) {
          float v = acc[mi][ni][r] + bval;
          if (RELU) v = fmaxf(v, 0.f);
          if (SPLITOUT) {
            if (colg < 256) Cb[(size_t)rowg * 256 + colg] = f2bf(v);
            else Cf[(size_t)rowg * 256 + (colg - 256)] = v;
          } else if (OUT_BF16) {
            Cb[(size_t)rowg * N + colg] = f2bf(v);
          } else {
            Cf[(size_t)rowg * N + colg] = v;
          }
        }
      }
    }
  }
}

extern "C" void kernel_launch(void* const* d_in, const int* in_sizes, int n_in,
                              void* d_out, int out_size, void* d_ws, size_t ws_size,
                              hipStream_t stream) {
  const float* x = (const float*)d_in[0];
  const int* ei = (const int*)d_in[1];  // int32 per harness, [2][E]
  const float* W1l = (const float*)d_in[2];
  const float* b1 = (const float*)d_in[3];
  const float* W1r = (const float*)d_in[4];
  const float* W2l = (const float*)d_in[5];
  const float* b2 = (const float*)d_in[6];
  const float* W2r = (const float*)d_in[7];
  float* out = (float*)d_out;

  char* ws = (char*)d_ws;
  size_t off = 0;
  auto alloc = [&](size_t bytes) {
    void* p = ws + off;
    off = (off + bytes + 255) & ~(size_t)255;
    return p;
  };
  int* deg = (int*)alloc((size_t)N_NODES * 4);
  int* rowptr = (int*)alloc((size_t)(N_NODES + 1) * 4);
  int* cursor = (int*)alloc((size_t)N_NODES * 4);
  int* col = (int*)alloc((size_t)N_EDGES * 4);
  ushort_t* x_bf = (ushort_t*)alloc((size_t)N_NODES * F_IN * 2);
  ushort_t* aggx_bf = (ushort_t*)alloc((size_t)N_NODES * F_IN * 2);
  ushort_t* h_bf = (ushort_t*)alloc((size_t)N_NODES * F_HID * 2);
  ushort_t* hl_bf = (ushort_t*)alloc((size_t)N_NODES * F_OUT * 2);  // h@W2l, bf16
  float* hr = (float*)alloc((size_t)N_NODES * F_OUT * 4);           // h@W2r + b2
  ushort_t* W1lt = (ushort_t*)alloc((size_t)F_HID * F_IN * 2);   // [512][128]
  ushort_t* W1rt = (ushort_t*)alloc((size_t)F_HID * F_IN * 2);   // [512][128]
  ushort_t* Wcatt = (ushort_t*)alloc((size_t)512 * F_HID * 2);   // [512][512]
  float* biascat = (float*)alloc(512 * 4);

  // CSR build
  hipMemsetAsync(deg, 0, (size_t)N_NODES * 4, stream);
  deg_kernel<<<(N_EDGES + 255) / 256, 256, 0, stream>>>(ei, deg);
  scan_kernel<<<1, 1024, 0, stream>>>(deg, rowptr, cursor);
  fill_kernel<<<(N_EDGES + 255) / 256, 256, 0, stream>>>(ei, cursor, col);

  // Conversions (independent of CSR)
  cvt_x_kernel<<<(N_NODES * F_IN / 4 + 255) / 256, 256, 0, stream>>>(x, x_bf);
  wt_kernel<<<(F_IN * F_HID + 255) / 256, 256, 0, stream>>>(W1l, W1lt, F_IN, F_HID, 0, F_IN);
  wt_kernel<<<(F_IN * F_HID + 255) / 256, 256, 0, stream>>>(W1r, W1rt, F_IN, F_HID, 0, F_IN);
  wt_kernel<<<(F_HID * F_OUT + 255) / 256, 256, 0, stream>>>(W2l, Wcatt, F_HID, F_OUT, 0, F_HID);
  wt_kernel<<<(F_HID * F_OUT + 255) / 256, 256, 0, stream>>>(W2r, Wcatt, F_HID, F_OUT, 256, F_HID);
  biascat_kernel<<<2, 256, 0, stream>>>(b2, biascat);

  // Layer 1: aggx_bf = mean-agg(x_bf); h_bf = relu(aggx@W1l + x@W1r + b1)
  agg1_kernel<<<N_NODES, 64, 0, stream>>>(x_bf, aggx_bf, rowptr, col);
  gemm_mfma<true, true, true, true, false>
      <<<dim3((N_NODES + 127) / 128, F_HID / 128), 256, 0, stream>>>(
          aggx_bf, x_bf, W1lt, W1rt, b1, nullptr, h_bf, N_NODES, F_HID, F_IN);

  // Layer 2 fused: [hl_bf | hr] = h_bf @ [W2l|W2r] + [0|b2], split outputs
  gemm_mfma<false, false, true, false, true>
      <<<dim3((N_NODES + 127) / 128, 512 / 128), 256, 0, stream>>>(
          h_bf, nullptr, Wcatt, nullptr, biascat, hr, hl_bf, N_NODES, 512, F_HID);
  // out = mean-agg(hl_bf) + hr
  agg2_kernel<<<N_NODES, 128, 0, stream>>>(hl_bf, hr, out, rowptr, col);
}

// Round 5
// 384.421 us; speedup vs baseline: 1.9960x; 1.0322x over previous
//
#include <hip/hip_runtime.h>

// GraphSAGE 2-layer. N=40000, E=640000, 128 -> 512 (relu) -> 256.
// Round 5: swapped-operand MFMA (mfma(bv, av, acc)) so each lane's acc frag
// holds 4 CONSECUTIVE output columns of one row -> vectorized epilogue
// (ushort4/float4 stores, float4 bias) instead of 64 scalar strided stores.
// Layer-2 gather path in bf16 (hl_bf compact), agg kernels uint-vectorized.
// absmax budget 0.102; round-4 measured 0.031.

#define N_NODES 40000
#define N_EDGES 640000
#define F_IN 128
#define F_HID 512
#define F_OUT 256

typedef unsigned short ushort_t;
typedef __attribute__((ext_vector_type(8))) short bf16x8;
typedef __attribute__((ext_vector_type(4))) float floatx4;

__device__ __forceinline__ ushort_t f2bf(float f) {
  union { float f; unsigned int u; } x; x.f = f;
  unsigned int r = (x.u + 0x7FFFu + ((x.u >> 16) & 1u)) >> 16;  // RNE
  return (ushort_t)r;
}
__device__ __forceinline__ float bf2f(ushort_t u) {
  union { unsigned int u; float f; } x; x.u = ((unsigned int)u) << 16;
  return x.f;
}

// ---------------- CSR build ----------------
__global__ void deg_kernel(const int* __restrict__ ei, int* __restrict__ deg) {
  int e = blockIdx.x * blockDim.x + threadIdx.x;
  if (e < N_EDGES) atomicAdd(&deg[ei[N_EDGES + e]], 1);
}

// One block, 1024 threads, 40 elems/thread + one block-wide scan.
__global__ __launch_bounds__(1024) void scan_kernel(const int* __restrict__ deg,
                                                    int* __restrict__ rowptr,
                                                    int* __restrict__ cursor) {
  const int PER = 40;  // 1024*40 = 40960 >= N_NODES+1
  __shared__ int buf[2][1024];
  int tid = threadIdx.x;
  int base = tid * PER;
  int loc[PER];
  int sum = 0;
  #pragma unroll
  for (int i = 0; i < PER; ++i) {
    int idx = base + i;
    int v = (idx < N_NODES) ? deg[idx] : 0;
    loc[i] = sum;  // exclusive within this thread's run
    sum += v;
  }
  buf[0][tid] = sum;
  __syncthreads();
  int cur = 0;
  #pragma unroll
  for (int off = 1; off < 1024; off <<= 1) {
    int val = buf[cur][tid];
    if (tid >= off) val += buf[cur][tid - off];
    buf[cur ^ 1][tid] = val;
    __syncthreads();
    cur ^= 1;
  }
  int excl = buf[cur][tid] - sum;  // exclusive prefix of this thread's run
  #pragma unroll
  for (int i = 0; i < PER; ++i) {
    int idx = base + i;
    if (idx < N_NODES) {
      int v = excl + loc[i];
      rowptr[idx] = v;
      cursor[idx] = v;
    } else if (idx == N_NODES) {
      rowptr[N_NODES] = excl + loc[i];  // == E
    }
  }
}

__global__ void fill_kernel(const int* __restrict__ ei, int* __restrict__ cursor,
                            int* __restrict__ col) {
  int e = blockIdx.x * blockDim.x + threadIdx.x;
  if (e < N_EDGES) {
    int d = ei[N_EDGES + e];
    int s = ei[e];
    int pos = atomicAdd(&cursor[d], 1);
    col[pos] = s;
  }
}

// ---------------- conversions ----------------
__global__ void cvt_x_kernel(const float* __restrict__ x, ushort_t* __restrict__ xb) {
  int i = blockIdx.x * blockDim.x + threadIdx.x;  // per float4
  const int n4 = (N_NODES * F_IN) / 4;
  if (i < n4) {
    float4 v = ((const float4*)x)[i];
    ushort4 o;
    o.x = f2bf(v.x); o.y = f2bf(v.y); o.z = f2bf(v.z); o.w = f2bf(v.w);
    ((ushort4*)xb)[i] = o;
  }
}

// Wt[(rowoff+n)*ldt + k] = bf16(W[k*N + n])   (transpose + convert)
__global__ void wt_kernel(const float* __restrict__ W, ushort_t* __restrict__ Wt,
                          int K, int N, int rowoff, int ldt) {
  int i = blockIdx.x * blockDim.x + threadIdx.x;  // i = n*K + k (coalesced write)
  if (i < K * N) {
    int n = i / K, k = i - n * K;
    Wt[(size_t)(rowoff + n) * ldt + k] = f2bf(W[(size_t)k * N + n]);
  }
}

__global__ void biascat_kernel(const float* __restrict__ b2, float* __restrict__ bc) {
  int i = threadIdx.x + blockIdx.x * blockDim.x;
  if (i < 512) bc[i] = (i < 256) ? 0.f : b2[i - 256];
}

// ---------------- aggregation ----------------
// Layer 1: bf16 in/out, F=128. One wave (64 thr) per node; each lane owns
// 2 adjacent cols via uint loads.
__global__ void agg1_kernel(const ushort_t* __restrict__ Xb, ushort_t* __restrict__ Yb,
                            const int* __restrict__ rowptr, const int* __restrict__ colidx) {
  __shared__ int cols[64];
  int n = blockIdx.x, f = threadIdx.x;
  int s = rowptr[n], e = rowptr[n + 1];
  float s0 = 0.f, s1 = 0.f;
  for (int base = s; base < e; base += 64) {
    int cnt = min(64, e - base);
    __syncthreads();
    if (f < cnt) cols[f] = colidx[base + f];
    __syncthreads();
    for (int j = 0; j < cnt; ++j) {
      unsigned int v = *(const unsigned int*)(Xb + (size_t)cols[j] * F_IN + 2 * f);
      s0 += bf2f((ushort_t)(v & 0xffffu));
      s1 += bf2f((ushort_t)(v >> 16));
    }
  }
  float inv = 1.f / fmaxf((float)(e - s), 1.f);
  unsigned int o = (unsigned int)f2bf(s0 * inv) | ((unsigned int)f2bf(s1 * inv) << 16);
  *(unsigned int*)(Yb + (size_t)n * F_IN + 2 * f) = o;
}

// Layer 2: gather compact bf16 hl rows (512B each), add fp32 hr[n], write fp32 out.
// 128 threads per node; each lane owns 2 adjacent cols.
__global__ void agg2_kernel(const ushort_t* __restrict__ hl, const float* __restrict__ hr,
                            float* __restrict__ out,
                            const int* __restrict__ rowptr, const int* __restrict__ colidx) {
  __shared__ int cols[128];
  int n = blockIdx.x, f = threadIdx.x;
  int s = rowptr[n], e = rowptr[n + 1];
  float s0 = 0.f, s1 = 0.f;
  for (int base = s; base < e; base += 128) {
    int cnt = min(128, e - base);
    __syncthreads();
    if (f < cnt) cols[f] = colidx[base + f];
    __syncthreads();
    for (int j = 0; j < cnt; ++j) {
      unsigned int v = *(const unsigned int*)(hl + (size_t)cols[j] * F_OUT + 2 * f);
      s0 += bf2f((ushort_t)(v & 0xffffu));
      s1 += bf2f((ushort_t)(v >> 16));
    }
  }
  float inv = 1.f / fmaxf((float)(e - s), 1.f);
  float2 hrv = *(const float2*)(hr + (size_t)n * F_OUT + 2 * f);
  float2 o;
  o.x = s0 * inv + hrv.x;
  o.y = s1 * inv + hrv.y;
  *(float2*)(out + (size_t)n * F_OUT + 2 * f) = o;
}

// ---------------- bf16 MFMA GEMM ----------------
// C[M,N] = (sum p) A_p[M,K] @ W_p[K,N] (+bias)(relu), A bf16 row-major,
// W given TRANSPOSED bf16: Wt[n][k], row stride K.
// 128x128 tile, 4 waves (2x2), each wave 4x4 frags of 16x16x32.
// SWAPPED OPERANDS: acc[mi][ni] = mfma(bv[ni], av[mi], acc). With the
// B-fragment as the A-operand, D[i][j] = sum_k W[k][n0+i] * Act[m0+j][k],
// so per lane: output row m = m0 + (lane&15) is FIXED and the 4 regs are
// 4 consecutive output cols n = n0 + (lane>>4)*4 + reg -> vector stores.
// SPLITOUT (N==512 only): cols 0:256 -> Cb bf16 [M][256]; cols 256:512 -> Cf
// fp32 [M][256]. Split is block-uniform (tile BN=128 lies in one half).
template <bool TWOPAIR, bool RELU, bool BIAS, bool OUT_BF16, bool SPLITOUT>
__global__ __launch_bounds__(256) void gemm_mfma(
    const ushort_t* __restrict__ A0, const ushort_t* __restrict__ A1,
    const ushort_t* __restrict__ W0t, const ushort_t* __restrict__ W1t,
    const float* __restrict__ bias, float* __restrict__ Cf,
    ushort_t* __restrict__ Cb, int M, int N, int K) {
  const int BM = 128, BN = 128, BK = 32;
  __shared__ ushort_t At[BM * BK];  // [128 m][32 k]
  __shared__ ushort_t Bt[BN * BK];  // [128 n][32 k]
  const int tid = threadIdx.x;
  const int wave = tid >> 6, lane = tid & 63;
  const int lm = lane & 15, qk = lane >> 4;
  const int wm = wave & 1, wn = wave >> 1;
  const int bm = blockIdx.x * BM, bn = blockIdx.y * BN;
  floatx4 acc[4][4] = {};
  const int npair = TWOPAIR ? 2 : 1;
  for (int p = 0; p < npair; ++p) {
    const ushort_t* __restrict__ A = p ? A1 : A0;
    const ushort_t* __restrict__ Wt = p ? W1t : W0t;
    for (int kb = 0; kb < K; kb += BK) {
      // Stage 8KB A-tile + 8KB B-tile via global_load_lds width=16.
      #pragma unroll
      for (int pass = 0; pass < 2; ++pass) {
        int c = pass * 256 + wave * 64 + lane;
        int row = c >> 2, kc = c & 3;
        int ar = min(bm + row, M - 1);  // clamp tail rows (stores are guarded)
        const ushort_t* ga = A + (size_t)ar * K + kb + kc * 8;
        const ushort_t* gb = Wt + (size_t)(bn + row) * K + kb + kc * 8;
        ushort_t* la = At + (size_t)(pass * 256 + wave * 64) * 8;
        ushort_t* lb = Bt + (size_t)(pass * 256 + wave * 64) * 8;
        __builtin_amdgcn_global_load_lds(
            (const __attribute__((address_space(1))) void*)ga,
            (__attribute__((address_space(3))) void*)la, 16, 0, 0);
        __builtin_amdgcn_global_load_lds(
            (const __attribute__((address_space(1))) void*)gb,
            (__attribute__((address_space(3))) void*)lb, 16, 0, 0);
      }
      __syncthreads();
      bf16x8 av[4], bv[4];
      #pragma unroll
      for (int mi = 0; mi < 4; ++mi)
        av[mi] = *(const bf16x8*)(At + (wm * 64 + mi * 16 + lm) * BK + qk * 8);
      #pragma unroll
      for (int ni = 0; ni < 4; ++ni)
        bv[ni] = *(const bf16x8*)(Bt + (wn * 64 + ni * 16 + lm) * BK + qk * 8);
      #pragma unroll
      for (int mi = 0; mi < 4; ++mi)
        #pragma unroll
        for (int ni = 0; ni < 4; ++ni)
          acc[mi][ni] = __builtin_amdgcn_mfma_f32_16x16x32_bf16(
              bv[ni], av[mi], acc[mi][ni], 0, 0, 0);  // swapped operands
      __syncthreads();
    }
  }
  // Epilogue (swapped layout): lane's output row m = bm + wm*64 + mi*16 + lm,
  // cols n = bn + wn*64 + ni*16 + qk*4 + {0,1,2,3} (contiguous).
  #pragma unroll
  for (int ni = 0; ni < 4; ++ni) {
    int colg = bn + wn * 64 + ni * 16 + qk * 4;  // 4-aligned
    float4 b4 = {0.f, 0.f, 0.f, 0.f};
    if (BIAS) b4 = *(const float4*)&bias[colg];
    #pragma unroll
    for (int mi = 0; mi < 4; ++mi) {
      int rowg = bm + wm * 64 + mi * 16 + lm;
      if (rowg < M) {
        float v0 = acc[mi][ni][0] + b4.x;
        float v1 = acc[mi][ni][1] + b4.y;
        float v2 = acc[mi][ni][2] + b4.z;
        float v3 = acc[mi][ni][3] + b4.w;
        if (RELU) {
          v0 = fmaxf(v0, 0.f); v1 = fmaxf(v1, 0.f);
          v2 = fmaxf(v2, 0.f); v3 = fmaxf(v3, 0.f);
        }
        if (SPLITOUT) {
          if (colg < 256) {
            ushort4 o = {f2bf(v0), f2bf(v1), f2bf(v2), f2bf(v3)};
            *(ushort4*)&Cb[(size_t)rowg * 256 + colg] = o;
          } else {
            float4 o = {v0, v1, v2, v3};
            *(float4*)&Cf[(size_t)rowg * 256 + (colg - 256)] = o;
          }
        } else if (OUT_BF16) {
          ushort4 o = {f2bf(v0), f2bf(v1), f2bf(v2), f2bf(v3)};
          *(ushort4*)&Cb[(size_t)rowg * N + colg] = o;
        } else {
          float4 o = {v0, v1, v2, v3};
          *(float4*)&Cf[(size_t)rowg * N + colg] = o;
        }
      }
    }
  }
}

extern "C" void kernel_launch(void* const* d_in, const int* in_sizes, int n_in,
                              void* d_out, int out_size, void* d_ws, size_t ws_size,
                              hipStream_t stream) {
  const float* x = (const float*)d_in[0];
  const int* ei = (const int*)d_in[1];  // int32 per harness, [2][E]
  const float* W1l = (const float*)d_in[2];
  const float* b1 = (const float*)d_in[3];
  const float* W1r = (const float*)d_in[4];
  const float* W2l = (const float*)d_in[5];
  const float* b2 = (const float*)d_in[6];
  const float* W2r = (const float*)d_in[7];
  float* out = (float*)d_out;

  char* ws = (char*)d_ws;
  size_t off = 0;
  auto alloc = [&](size_t bytes) {
    void* p = ws + off;
    off = (off + bytes + 255) & ~(size_t)255;
    return p;
  };
  int* deg = (int*)alloc((size_t)N_NODES * 4);
  int* rowptr = (int*)alloc((size_t)(N_NODES + 1) * 4);
  int* cursor = (int*)alloc((size_t)N_NODES * 4);
  int* col = (int*)alloc((size_t)N_EDGES * 4);
  ushort_t* x_bf = (ushort_t*)alloc((size_t)N_NODES * F_IN * 2);
  ushort_t* aggx_bf = (ushort_t*)alloc((size_t)N_NODES * F_IN * 2);
  ushort_t* h_bf = (ushort_t*)alloc((size_t)N_NODES * F_HID * 2);
  ushort_t* hl_bf = (ushort_t*)alloc((size_t)N_NODES * F_OUT * 2);  // h@W2l, bf16
  float* hr = (float*)alloc((size_t)N_NODES * F_OUT * 4);           // h@W2r + b2
  ushort_t* W1lt = (ushort_t*)alloc((size_t)F_HID * F_IN * 2);   // [512][128]
  ushort_t* W1rt = (ushort_t*)alloc((size_t)F_HID * F_IN * 2);   // [512][128]
  ushort_t* Wcatt = (ushort_t*)alloc((size_t)512 * F_HID * 2);   // [512][512]
  float* biascat = (float*)alloc(512 * 4);

  // CSR build
  hipMemsetAsync(deg, 0, (size_t)N_NODES * 4, stream);
  deg_kernel<<<(N_EDGES + 255) / 256, 256, 0, stream>>>(ei, deg);
  scan_kernel<<<1, 1024, 0, stream>>>(deg, rowptr, cursor);
  fill_kernel<<<(N_EDGES + 255) / 256, 256, 0, stream>>>(ei, cursor, col);

  // Conversions (independent of CSR)
  cvt_x_kernel<<<(N_NODES * F_IN / 4 + 255) / 256, 256, 0, stream>>>(x, x_bf);
  wt_kernel<<<(F_IN * F_HID + 255) / 256, 256, 0, stream>>>(W1l, W1lt, F_IN, F_HID, 0, F_IN);
  wt_kernel<<<(F_IN * F_HID + 255) / 256, 256, 0, stream>>>(W1r, W1rt, F_IN, F_HID, 0, F_IN);
  wt_kernel<<<(F_HID * F_OUT + 255) / 256, 256, 0, stream>>>(W2l, Wcatt, F_HID, F_OUT, 0, F_HID);
  wt_kernel<<<(F_HID * F_OUT + 255) / 256, 256, 0, stream>>>(W2r, Wcatt, F_HID, F_OUT, 256, F_HID);
  biascat_kernel<<<2, 256, 0, stream>>>(b2, biascat);

  // Layer 1: aggx_bf = mean-agg(x_bf); h_bf = relu(aggx@W1l + x@W1r + b1)
  agg1_kernel<<<N_NODES, 64, 0, stream>>>(x_bf, aggx_bf, rowptr, col);
  gemm_mfma<true, true, true, true, false>
      <<<dim3((N_NODES + 127) / 128, F_HID / 128), 256, 0, stream>>>(
          aggx_bf, x_bf, W1lt, W1rt, b1, nullptr, h_bf, N_NODES, F_HID, F_IN);

  // Layer 2 fused: [hl_bf | hr] = h_bf @ [W2l|W2r] + [0|b2], split outputs
  gemm_mfma<false, false, true, false, true>
      <<<dim3((N_NODES + 127) / 128, 512 / 128), 256, 0, stream>>>(
          h_bf, nullptr, Wcatt, nullptr, biascat, hr, hl_bf, N_NODES, 512, F_HID);
  // out = mean-agg(hl_bf) + hr
  agg2_kernel<<<N_NODES, 128, 0, stream>>>(hl_bf, hr, out, rowptr, col);
}

// Round 6
// 332.031 us; speedup vs baseline: 2.3110x; 1.1578x over previous
//
#include <hip/hip_runtime.h>

// GraphSAGE 2-layer. N=40000, E=640000, 128 -> 512 (relu) -> 256.
// Round 6: hierarchical 3-kernel scan (157-block reduce -> 1-block scan ->
// 157-block rescan) replacing the single-block PER=40 scan whose loc[]
// array spilled to scratch (64 us, 0.1% occupancy). Swapped-operand MFMA
// epilogue (vector stores), bf16 layer-2 gather path. absmax 0.031/0.102.

#define N_NODES 40000
#define N_EDGES 640000
#define F_IN 128
#define F_HID 512
#define F_OUT 256
#define NB_SCAN 157  // ceil(40000/256)

typedef unsigned short ushort_t;
typedef __attribute__((ext_vector_type(8))) short bf16x8;
typedef __attribute__((ext_vector_type(4))) float floatx4;

__device__ __forceinline__ ushort_t f2bf(float f) {
  union { float f; unsigned int u; } x; x.f = f;
  unsigned int r = (x.u + 0x7FFFu + ((x.u >> 16) & 1u)) >> 16;  // RNE
  return (ushort_t)r;
}
__device__ __forceinline__ float bf2f(ushort_t u) {
  union { unsigned int u; float f; } x; x.u = ((unsigned int)u) << 16;
  return x.f;
}

// ---------------- CSR build ----------------
__global__ void deg_kernel(const int* __restrict__ ei, int* __restrict__ deg) {
  int e = blockIdx.x * blockDim.x + threadIdx.x;
  if (e < N_EDGES) atomicAdd(&deg[ei[N_EDGES + e]], 1);
}

// A: per-block reduction of deg -> bsum[NB_SCAN]
__global__ void scanA_kernel(const int* __restrict__ deg, int* __restrict__ bsum) {
  __shared__ int sdata[256];
  int i = blockIdx.x * 256 + threadIdx.x;
  sdata[threadIdx.x] = (i < N_NODES) ? deg[i] : 0;
  __syncthreads();
  #pragma unroll
  for (int off = 128; off > 0; off >>= 1) {
    if (threadIdx.x < off) sdata[threadIdx.x] += sdata[threadIdx.x + off];
    __syncthreads();
  }
  if (threadIdx.x == 0) bsum[blockIdx.x] = sdata[0];
}

// B: single-block exclusive scan of the NB_SCAN block sums
__global__ void scanB_kernel(const int* __restrict__ bsum, int* __restrict__ boff) {
  __shared__ int buf[2][256];
  int tid = threadIdx.x;
  int v = (tid < NB_SCAN) ? bsum[tid] : 0;
  buf[0][tid] = v;
  __syncthreads();
  int cur = 0;
  #pragma unroll
  for (int off = 1; off < 256; off <<= 1) {
    int val = buf[cur][tid];
    if (tid >= off) val += buf[cur][tid - off];
    buf[cur ^ 1][tid] = val;
    __syncthreads();
    cur ^= 1;
  }
  if (tid < NB_SCAN) boff[tid] = buf[cur][tid] - v;  // exclusive
}

// C: block-local exclusive scan + boff -> rowptr, cursor
__global__ void scanC_kernel(const int* __restrict__ deg, const int* __restrict__ boff,
                             int* __restrict__ rowptr, int* __restrict__ cursor) {
  __shared__ int buf[2][256];
  int tid = threadIdx.x;
  int i = blockIdx.x * 256 + tid;
  int v = (i < N_NODES) ? deg[i] : 0;
  buf[0][tid] = v;
  __syncthreads();
  int cur = 0;
  #pragma unroll
  for (int off = 1; off < 256; off <<= 1) {
    int val = buf[cur][tid];
    if (tid >= off) val += buf[cur][tid - off];
    buf[cur ^ 1][tid] = val;
    __syncthreads();
    cur ^= 1;
  }
  if (i < N_NODES) {
    int ex = boff[blockIdx.x] + buf[cur][tid] - v;
    rowptr[i] = ex;
    cursor[i] = ex;
    if (i == N_NODES - 1) rowptr[N_NODES] = ex + v;  // == E
  }
}

__global__ void fill_kernel(const int* __restrict__ ei, int* __restrict__ cursor,
                            int* __restrict__ col) {
  int e = blockIdx.x * blockDim.x + threadIdx.x;
  if (e < N_EDGES) {
    int d = ei[N_EDGES + e];
    int s = ei[e];
    int pos = atomicAdd(&cursor[d], 1);
    col[pos] = s;
  }
}

// ---------------- conversions ----------------
__global__ void cvt_x_kernel(const float* __restrict__ x, ushort_t* __restrict__ xb) {
  int i = blockIdx.x * blockDim.x + threadIdx.x;  // per float4
  const int n4 = (N_NODES * F_IN) / 4;
  if (i < n4) {
    float4 v = ((const float4*)x)[i];
    ushort4 o;
    o.x = f2bf(v.x); o.y = f2bf(v.y); o.z = f2bf(v.z); o.w = f2bf(v.w);
    ((ushort4*)xb)[i] = o;
  }
}

// Wt[(rowoff+n)*ldt + k] = bf16(W[k*N + n])   (transpose + convert)
__global__ void wt_kernel(const float* __restrict__ W, ushort_t* __restrict__ Wt,
                          int K, int N, int rowoff, int ldt) {
  int i = blockIdx.x * blockDim.x + threadIdx.x;  // i = n*K + k (coalesced write)
  if (i < K * N) {
    int n = i / K, k = i - n * K;
    Wt[(size_t)(rowoff + n) * ldt + k] = f2bf(W[(size_t)k * N + n]);
  }
}

__global__ void biascat_kernel(const float* __restrict__ b2, float* __restrict__ bc) {
  int i = threadIdx.x + blockIdx.x * blockDim.x;
  if (i < 512) bc[i] = (i < 256) ? 0.f : b2[i - 256];
}

// ---------------- aggregation ----------------
// Layer 1: bf16 in/out, F=128. One wave (64 thr) per node; each lane owns
// 2 adjacent cols via uint loads.
__global__ void agg1_kernel(const ushort_t* __restrict__ Xb, ushort_t* __restrict__ Yb,
                            const int* __restrict__ rowptr, const int* __restrict__ colidx) {
  __shared__ int cols[64];
  int n = blockIdx.x, f = threadIdx.x;
  int s = rowptr[n], e = rowptr[n + 1];
  float s0 = 0.f, s1 = 0.f;
  for (int base = s; base < e; base += 64) {
    int cnt = min(64, e - base);
    __syncthreads();
    if (f < cnt) cols[f] = colidx[base + f];
    __syncthreads();
    for (int j = 0; j < cnt; ++j) {
      unsigned int v = *(const unsigned int*)(Xb + (size_t)cols[j] * F_IN + 2 * f);
      s0 += bf2f((ushort_t)(v & 0xffffu));
      s1 += bf2f((ushort_t)(v >> 16));
    }
  }
  float inv = 1.f / fmaxf((float)(e - s), 1.f);
  unsigned int o = (unsigned int)f2bf(s0 * inv) | ((unsigned int)f2bf(s1 * inv) << 16);
  *(unsigned int*)(Yb + (size_t)n * F_IN + 2 * f) = o;
}

// Layer 2: gather compact bf16 hl rows (512B each), add fp32 hr[n], write fp32 out.
// 128 threads per node; each lane owns 2 adjacent cols.
__global__ void agg2_kernel(const ushort_t* __restrict__ hl, const float* __restrict__ hr,
                            float* __restrict__ out,
                            const int* __restrict__ rowptr, const int* __restrict__ colidx) {
  __shared__ int cols[128];
  int n = blockIdx.x, f = threadIdx.x;
  int s = rowptr[n], e = rowptr[n + 1];
  float s0 = 0.f, s1 = 0.f;
  for (int base = s; base < e; base += 128) {
    int cnt = min(128, e - base);
    __syncthreads();
    if (f < cnt) cols[f] = colidx[base + f];
    __syncthreads();
    for (int j = 0; j < cnt; ++j) {
      unsigned int v = *(const unsigned int*)(hl + (size_t)cols[j] * F_OUT + 2 * f);
      s0 += bf2f((ushort_t)(v & 0xffffu));
      s1 += bf2f((ushort_t)(v >> 16));
    }
  }
  float inv = 1.f / fmaxf((float)(e - s), 1.f);
  float2 hrv = *(const float2*)(hr + (size_t)n * F_OUT + 2 * f);
  float2 o;
  o.x = s0 * inv + hrv.x;
  o.y = s1 * inv + hrv.y;
  *(float2*)(out + (size_t)n * F_OUT + 2 * f) = o;
}

// ---------------- bf16 MFMA GEMM ----------------
// C[M,N] = (sum p) A_p[M,K] @ W_p[K,N] (+bias)(relu), A bf16 row-major,
// W given TRANSPOSED bf16: Wt[n][k], row stride K.
// 128x128 tile, 4 waves (2x2), each wave 4x4 frags of 16x16x32.
// SWAPPED OPERANDS: acc[mi][ni] = mfma(bv[ni], av[mi], acc) -> per lane the
// output row m = m0 + (lane&15) is FIXED and the 4 acc regs are 4 consecutive
// output cols -> vector stores in the epilogue.
// SPLITOUT (N==512 only): cols 0:256 -> Cb bf16 [M][256]; cols 256:512 -> Cf
// fp32 [M][256]. Split is block-uniform (tile BN=128 lies in one half).
template <bool TWOPAIR, bool RELU, bool BIAS, bool OUT_BF16, bool SPLITOUT>
__global__ __launch_bounds__(256) void gemm_mfma(
    const ushort_t* __restrict__ A0, const ushort_t* __restrict__ A1,
    const ushort_t* __restrict__ W0t, const ushort_t* __restrict__ W1t,
    const float* __restrict__ bias, float* __restrict__ Cf,
    ushort_t* __restrict__ Cb, int M, int N, int K) {
  const int BM = 128, BN = 128, BK = 32;
  __shared__ ushort_t At[BM * BK];  // [128 m][32 k]
  __shared__ ushort_t Bt[BN * BK];  // [128 n][32 k]
  const int tid = threadIdx.x;
  const int wave = tid >> 6, lane = tid & 63;
  const int lm = lane & 15, qk = lane >> 4;
  const int wm = wave & 1, wn = wave >> 1;
  const int bm = blockIdx.x * BM, bn = blockIdx.y * BN;
  floatx4 acc[4][4] = {};
  const int npair = TWOPAIR ? 2 : 1;
  for (int p = 0; p < npair; ++p) {
    const ushort_t* __restrict__ A = p ? A1 : A0;
    const ushort_t* __restrict__ Wt = p ? W1t : W0t;
    for (int kb = 0; kb < K; kb += BK) {
      // Stage 8KB A-tile + 8KB B-tile via global_load_lds width=16.
      #pragma unroll
      for (int pass = 0; pass < 2; ++pass) {
        int c = pass * 256 + wave * 64 + lane;
        int row = c >> 2, kc = c & 3;
        int ar = min(bm + row, M - 1);  // clamp tail rows (stores are guarded)
        const ushort_t* ga = A + (size_t)ar * K + kb + kc * 8;
        const ushort_t* gb = Wt + (size_t)(bn + row) * K + kb + kc * 8;
        ushort_t* la = At + (size_t)(pass * 256 + wave * 64) * 8;
        ushort_t* lb = Bt + (size_t)(pass * 256 + wave * 64) * 8;
        __builtin_amdgcn_global_load_lds(
            (const __attribute__((address_space(1))) void*)ga,
            (__attribute__((address_space(3))) void*)la, 16, 0, 0);
        __builtin_amdgcn_global_load_lds(
            (const __attribute__((address_space(1))) void*)gb,
            (__attribute__((address_space(3))) void*)lb, 16, 0, 0);
      }
      __syncthreads();
      bf16x8 av[4], bv[4];
      #pragma unroll
      for (int mi = 0; mi < 4; ++mi)
        av[mi] = *(const bf16x8*)(At + (wm * 64 + mi * 16 + lm) * BK + qk * 8);
      #pragma unroll
      for (int ni = 0; ni < 4; ++ni)
        bv[ni] = *(const bf16x8*)(Bt + (wn * 64 + ni * 16 + lm) * BK + qk * 8);
      #pragma unroll
      for (int mi = 0; mi < 4; ++mi)
        #pragma unroll
        for (int ni = 0; ni < 4; ++ni)
          acc[mi][ni] = __builtin_amdgcn_mfma_f32_16x16x32_bf16(
              bv[ni], av[mi], acc[mi][ni], 0, 0, 0);  // swapped operands
      __syncthreads();
    }
  }
  // Epilogue (swapped layout): lane's output row m = bm + wm*64 + mi*16 + lm,
  // cols n = bn + wn*64 + ni*16 + qk*4 + {0,1,2,3} (contiguous).
  #pragma unroll
  for (int ni = 0; ni < 4; ++ni) {
    int colg = bn + wn * 64 + ni * 16 + qk * 4;  // 4-aligned
    float4 b4 = {0.f, 0.f, 0.f, 0.f};
    if (BIAS) b4 = *(const float4*)&bias[colg];
    #pragma unroll
    for (int mi = 0; mi < 4; ++mi) {
      int rowg = bm + wm * 64 + mi * 16 + lm;
      if (rowg < M) {
        float v0 = acc[mi][ni][0] + b4.x;
        float v1 = acc[mi][ni][1] + b4.y;
        float v2 = acc[mi][ni][2] + b4.z;
        float v3 = acc[mi][ni][3] + b4.w;
        if (RELU) {
          v0 = fmaxf(v0, 0.f); v1 = fmaxf(v1, 0.f);
          v2 = fmaxf(v2, 0.f); v3 = fmaxf(v3, 0.f);
        }
        if (SPLITOUT) {
          if (colg < 256) {
            ushort4 o = {f2bf(v0), f2bf(v1), f2bf(v2), f2bf(v3)};
            *(ushort4*)&Cb[(size_t)rowg * 256 + colg] = o;
          } else {
            float4 o = {v0, v1, v2, v3};
            *(float4*)&Cf[(size_t)rowg * 256 + (colg - 256)] = o;
          }
        } else if (OUT_BF16) {
          ushort4 o = {f2bf(v0), f2bf(v1), f2bf(v2), f2bf(v3)};
          *(ushort4*)&Cb[(size_t)rowg * N + colg] = o;
        } else {
          float4 o = {v0, v1, v2, v3};
          *(float4*)&Cf[(size_t)rowg * N + colg] = o;
        }
      }
    }
  }
}

extern "C" void kernel_launch(void* const* d_in, const int* in_sizes, int n_in,
                              void* d_out, int out_size, void* d_ws, size_t ws_size,
                              hipStream_t stream) {
  const float* x = (const float*)d_in[0];
  const int* ei = (const int*)d_in[1];  // int32 per harness, [2][E]
  const float* W1l = (const float*)d_in[2];
  const float* b1 = (const float*)d_in[3];
  const float* W1r = (const float*)d_in[4];
  const float* W2l = (const float*)d_in[5];
  const float* b2 = (const float*)d_in[6];
  const float* W2r = (const float*)d_in[7];
  float* out = (float*)d_out;

  char* ws = (char*)d_ws;
  size_t off = 0;
  auto alloc = [&](size_t bytes) {
    void* p = ws + off;
    off = (off + bytes + 255) & ~(size_t)255;
    return p;
  };
  int* deg = (int*)alloc((size_t)N_NODES * 4);
  int* rowptr = (int*)alloc((size_t)(N_NODES + 1) * 4);
  int* cursor = (int*)alloc((size_t)N_NODES * 4);
  int* col = (int*)alloc((size_t)N_EDGES * 4);
  int* bsum = (int*)alloc((size_t)NB_SCAN * 4);
  int* boff = (int*)alloc((size_t)NB_SCAN * 4);
  ushort_t* x_bf = (ushort_t*)alloc((size_t)N_NODES * F_IN * 2);
  ushort_t* aggx_bf = (ushort_t*)alloc((size_t)N_NODES * F_IN * 2);
  ushort_t* h_bf = (ushort_t*)alloc((size_t)N_NODES * F_HID * 2);
  ushort_t* hl_bf = (ushort_t*)alloc((size_t)N_NODES * F_OUT * 2);  // h@W2l, bf16
  float* hr = (float*)alloc((size_t)N_NODES * F_OUT * 4);           // h@W2r + b2
  ushort_t* W1lt = (ushort_t*)alloc((size_t)F_HID * F_IN * 2);   // [512][128]
  ushort_t* W1rt = (ushort_t*)alloc((size_t)F_HID * F_IN * 2);   // [512][128]
  ushort_t* Wcatt = (ushort_t*)alloc((size_t)512 * F_HID * 2);   // [512][512]
  float* biascat = (float*)alloc(512 * 4);

  // CSR build
  hipMemsetAsync(deg, 0, (size_t)N_NODES * 4, stream);
  deg_kernel<<<(N_EDGES + 255) / 256, 256, 0, stream>>>(ei, deg);
  scanA_kernel<<<NB_SCAN, 256, 0, stream>>>(deg, bsum);
  scanB_kernel<<<1, 256, 0, stream>>>(bsum, boff);
  scanC_kernel<<<NB_SCAN, 256, 0, stream>>>(deg, boff, rowptr, cursor);
  fill_kernel<<<(N_EDGES + 255) / 256, 256, 0, stream>>>(ei, cursor, col);

  // Conversions (independent of CSR)
  cvt_x_kernel<<<(N_NODES * F_IN / 4 + 255) / 256, 256, 0, stream>>>(x, x_bf);
  wt_kernel<<<(F_IN * F_HID + 255) / 256, 256, 0, stream>>>(W1l, W1lt, F_IN, F_HID, 0, F_IN);
  wt_kernel<<<(F_IN * F_HID + 255) / 256, 256, 0, stream>>>(W1r, W1rt, F_IN, F_HID, 0, F_IN);
  wt_kernel<<<(F_HID * F_OUT + 255) / 256, 256, 0, stream>>>(W2l, Wcatt, F_HID, F_OUT, 0, F_HID);
  wt_kernel<<<(F_HID * F_OUT + 255) / 256, 256, 0, stream>>>(W2r, Wcatt, F_HID, F_OUT, 256, F_HID);
  biascat_kernel<<<2, 256, 0, stream>>>(b2, biascat);

  // Layer 1: aggx_bf = mean-agg(x_bf); h_bf = relu(aggx@W1l + x@W1r + b1)
  agg1_kernel<<<N_NODES, 64, 0, stream>>>(x_bf, aggx_bf, rowptr, col);
  gemm_mfma<true, true, true, true, false>
      <<<dim3((N_NODES + 127) / 128, F_HID / 128), 256, 0, stream>>>(
          aggx_bf, x_bf, W1lt, W1rt, b1, nullptr, h_bf, N_NODES, F_HID, F_IN);

  // Layer 2 fused: [hl_bf | hr] = h_bf @ [W2l|W2r] + [0|b2], split outputs
  gemm_mfma<false, false, true, false, true>
      <<<dim3((N_NODES + 127) / 128, 512 / 128), 256, 0, stream>>>(
          h_bf, nullptr, Wcatt, nullptr, biascat, hr, hl_bf, N_NODES, 512, F_HID);
  // out = mean-agg(hl_bf) + hr
  agg2_kernel<<<N_NODES, 128, 0, stream>>>(hl_bf, hr, out, rowptr, col);
}

// Round 7
// 325.869 us; speedup vs baseline: 2.3547x; 1.0189x over previous
//
#include <hip/hip_runtime.h>

// GraphSAGE 2-layer. N=40000, E=640000, 128 -> 512 (relu) -> 256.
// Round 7: persistent A-panel GEMM. BM=64 so a block's whole A panel
// (64 x K bf16 = 32/64 KB) is staged into LDS ONCE (kc-major via ds_write);
// the K-loop stages only the 16 KB B-tile (weights are L2-hot) via
// global_load_lds -> per-iter barrier drain is ~L2 latency, not HBM.
// LDS 64+16 KB = 80 KB exactly -> 2 blocks/CU. Layer-1's two K=128 pairs
// fused into one K=256 panel with [W1l^T|W1r^T]. Grid (2,625), no M tail.

#define N_NODES 40000
#define N_EDGES 640000
#define F_IN 128
#define F_HID 512
#define F_OUT 256
#define NB_SCAN 157  // ceil(40000/256)

typedef unsigned short ushort_t;
typedef __attribute__((ext_vector_type(8))) short bf16x8;
typedef __attribute__((ext_vector_type(4))) float floatx4;

__device__ __forceinline__ ushort_t f2bf(float f) {
  union { float f; unsigned int u; } x; x.f = f;
  unsigned int r = (x.u + 0x7FFFu + ((x.u >> 16) & 1u)) >> 16;  // RNE
  return (ushort_t)r;
}
__device__ __forceinline__ float bf2f(ushort_t u) {
  union { unsigned int u; float f; } x; x.u = ((unsigned int)u) << 16;
  return x.f;
}

// ---------------- CSR build ----------------
__global__ void deg_kernel(const int* __restrict__ ei, int* __restrict__ deg) {
  int e = blockIdx.x * blockDim.x + threadIdx.x;
  if (e < N_EDGES) atomicAdd(&deg[ei[N_EDGES + e]], 1);
}

__global__ void scanA_kernel(const int* __restrict__ deg, int* __restrict__ bsum) {
  __shared__ int sdata[256];
  int i = blockIdx.x * 256 + threadIdx.x;
  sdata[threadIdx.x] = (i < N_NODES) ? deg[i] : 0;
  __syncthreads();
  #pragma unroll
  for (int off = 128; off > 0; off >>= 1) {
    if (threadIdx.x < off) sdata[threadIdx.x] += sdata[threadIdx.x + off];
    __syncthreads();
  }
  if (threadIdx.x == 0) bsum[blockIdx.x] = sdata[0];
}

__global__ void scanB_kernel(const int* __restrict__ bsum, int* __restrict__ boff) {
  __shared__ int buf[2][256];
  int tid = threadIdx.x;
  int v = (tid < NB_SCAN) ? bsum[tid] : 0;
  buf[0][tid] = v;
  __syncthreads();
  int cur = 0;
  #pragma unroll
  for (int off = 1; off < 256; off <<= 1) {
    int val = buf[cur][tid];
    if (tid >= off) val += buf[cur][tid - off];
    buf[cur ^ 1][tid] = val;
    __syncthreads();
    cur ^= 1;
  }
  if (tid < NB_SCAN) boff[tid] = buf[cur][tid] - v;  // exclusive
}

__global__ void scanC_kernel(const int* __restrict__ deg, const int* __restrict__ boff,
                             int* __restrict__ rowptr, int* __restrict__ cursor) {
  __shared__ int buf[2][256];
  int tid = threadIdx.x;
  int i = blockIdx.x * 256 + tid;
  int v = (i < N_NODES) ? deg[i] : 0;
  buf[0][tid] = v;
  __syncthreads();
  int cur = 0;
  #pragma unroll
  for (int off = 1; off < 256; off <<= 1) {
    int val = buf[cur][tid];
    if (tid >= off) val += buf[cur][tid - off];
    buf[cur ^ 1][tid] = val;
    __syncthreads();
    cur ^= 1;
  }
  if (i < N_NODES) {
    int ex = boff[blockIdx.x] + buf[cur][tid] - v;
    rowptr[i] = ex;
    cursor[i] = ex;
    if (i == N_NODES - 1) rowptr[N_NODES] = ex + v;  // == E
  }
}

__global__ void fill_kernel(const int* __restrict__ ei, int* __restrict__ cursor,
                            int* __restrict__ col) {
  int e = blockIdx.x * blockDim.x + threadIdx.x;
  if (e < N_EDGES) {
    int d = ei[N_EDGES + e];
    int s = ei[e];
    int pos = atomicAdd(&cursor[d], 1);
    col[pos] = s;
  }
}

// ---------------- conversions ----------------
__global__ void cvt_x_kernel(const float* __restrict__ x, ushort_t* __restrict__ xb) {
  int i = blockIdx.x * blockDim.x + threadIdx.x;  // per float4
  const int n4 = (N_NODES * F_IN) / 4;
  if (i < n4) {
    float4 v = ((const float4*)x)[i];
    ushort4 o;
    o.x = f2bf(v.x); o.y = f2bf(v.y); o.z = f2bf(v.z); o.w = f2bf(v.w);
    ((ushort4*)xb)[i] = o;
  }
}

// Wt[(rowoff+n)*ldt + koff + k] = bf16(W[k*N + n])  (transpose + convert + pack)
__global__ void wt_kernel(const float* __restrict__ W, ushort_t* __restrict__ Wt,
                          int K, int N, int rowoff, int koff, int ldt) {
  int i = blockIdx.x * blockDim.x + threadIdx.x;  // i = n*K + k (coalesced write)
  if (i < K * N) {
    int n = i / K, k = i - n * K;
    Wt[(size_t)(rowoff + n) * ldt + koff + k] = f2bf(W[(size_t)k * N + n]);
  }
}

__global__ void biascat_kernel(const float* __restrict__ b2, float* __restrict__ bc) {
  int i = threadIdx.x + blockIdx.x * blockDim.x;
  if (i < 512) bc[i] = (i < 256) ? 0.f : b2[i - 256];
}

// ---------------- aggregation ----------------
__global__ void agg1_kernel(const ushort_t* __restrict__ Xb, ushort_t* __restrict__ Yb,
                            const int* __restrict__ rowptr, const int* __restrict__ colidx) {
  __shared__ int cols[64];
  int n = blockIdx.x, f = threadIdx.x;
  int s = rowptr[n], e = rowptr[n + 1];
  float s0 = 0.f, s1 = 0.f;
  for (int base = s; base < e; base += 64) {
    int cnt = min(64, e - base);
    __syncthreads();
    if (f < cnt) cols[f] = colidx[base + f];
    __syncthreads();
    for (int j = 0; j < cnt; ++j) {
      unsigned int v = *(const unsigned int*)(Xb + (size_t)cols[j] * F_IN + 2 * f);
      s0 += bf2f((ushort_t)(v & 0xffffu));
      s1 += bf2f((ushort_t)(v >> 16));
    }
  }
  float inv = 1.f / fmaxf((float)(e - s), 1.f);
  unsigned int o = (unsigned int)f2bf(s0 * inv) | ((unsigned int)f2bf(s1 * inv) << 16);
  *(unsigned int*)(Yb + (size_t)n * F_IN + 2 * f) = o;
}

__global__ void agg2_kernel(const ushort_t* __restrict__ hl, const float* __restrict__ hr,
                            float* __restrict__ out,
                            const int* __restrict__ rowptr, const int* __restrict__ colidx) {
  __shared__ int cols[128];
  int n = blockIdx.x, f = threadIdx.x;
  int s = rowptr[n], e = rowptr[n + 1];
  float s0 = 0.f, s1 = 0.f;
  for (int base = s; base < e; base += 128) {
    int cnt = min(128, e - base);
    __syncthreads();
    if (f < cnt) cols[f] = colidx[base + f];
    __syncthreads();
    for (int j = 0; j < cnt; ++j) {
      unsigned int v = *(const unsigned int*)(hl + (size_t)cols[j] * F_OUT + 2 * f);
      s0 += bf2f((ushort_t)(v & 0xffffu));
      s1 += bf2f((ushort_t)(v >> 16));
    }
  }
  float inv = 1.f / fmaxf((float)(e - s), 1.f);
  float2 hrv = *(const float2*)(hr + (size_t)n * F_OUT + 2 * f);
  float2 o;
  o.x = s0 * inv + hrv.x;
  o.y = s1 * inv + hrv.y;
  *(float2*)(out + (size_t)n * F_OUT + 2 * f) = o;
}

// ---------------- bf16 MFMA GEMM, persistent A-panel ----------------
// C[M, 512] = Acat[M, KT] @ Wcat[KT, 512] (+bias)(relu). Acat = [A0 | A1]
// when TWOPAIR (K0 = KT/2 each). Wt given transposed: Wt[n][k], row stride KT.
// BM=64, BN=256, BK=32, 256 threads (4 waves, wave w owns cols w*64..w*64+63).
// A-panel (64 x KT) staged ONCE into LDS, kc-major: chunk (kc, row) at
// (kc*64 + row)*16B -> MFMA frag read = one aligned b128, b128-minimum banking.
// K-loop stages only the B-tile via global_load_lds (weights L2-resident).
// Swapped-operand MFMA: acc[mi][ni] = mfma(bv, av, acc) -> lane's 4 acc regs
// are 4 consecutive output cols of one row -> vector epilogue stores.
// SPLITOUT: N-block 0 -> Cb bf16 [M][256], N-block 1 -> Cf fp32 [M][256].
template <bool TWOPAIR, bool RELU, bool BIAS, bool OUT_BF16, bool SPLITOUT, int KT>
__global__ __launch_bounds__(256) void gemm_mfma(
    const ushort_t* __restrict__ A0, const ushort_t* __restrict__ A1,
    const ushort_t* __restrict__ Wt, const float* __restrict__ bias,
    float* __restrict__ Cf, ushort_t* __restrict__ Cb, int M) {
  const int BM = 64, BN = 256, BK = 32;
  const int NKC = KT / 8;            // 16B chunks per row
  __shared__ ushort_t Apan[64 * KT]; // kc-major: chunk (kc,row) at (kc*64+row)*8
  __shared__ ushort_t Bt[BN * BK];   // [n_local][32k] packed
  const int tid = threadIdx.x;
  const int wave = tid >> 6, lane = tid & 63;
  const int lm = lane & 15, qk = lane >> 4;
  const int bn = blockIdx.x * BN;    // N-block fastest -> sibling blocks share A
  const int bm = blockIdx.y * BM;    // 625 * 64 = 40000 exactly, no tail
  const int K0 = TWOPAIR ? KT / 2 : KT;
  const int K0c = K0 / 8;

  // ---- stage A panel once: coalesced global read -> ds_write kc-major ----
  #pragma unroll
  for (int q = 0; q < (64 * NKC) / 256; ++q) {
    int c = tid + q * 256;
    int kc = c & (NKC - 1);
    int row = c / NKC;
    const ushort_t* src = (TWOPAIR && kc >= K0c)
        ? A1 + (size_t)(bm + row) * K0 + (kc - K0c) * 8
        : A0 + (size_t)(bm + row) * K0 + kc * 8;
    bf16x8 v = *(const bf16x8*)src;
    *(bf16x8*)(Apan + ((size_t)kc * 64 + row) * 8) = v;
  }

  floatx4 acc[4][4] = {};
  for (int kb = 0; kb < KT; kb += BK) {
    // stage B tile: 256 n-rows x 32 k = 1024 chunks of 16B, 4 per thread
    #pragma unroll
    for (int q = 0; q < 4; ++q) {
      int c = q * 256 + wave * 64 + lane;
      int n = c >> 2, kc2 = c & 3;
      const ushort_t* gb = Wt + (size_t)(bn + n) * KT + kb + kc2 * 8;
      ushort_t* lb = Bt + (size_t)(q * 256 + wave * 64) * 8;
      __builtin_amdgcn_global_load_lds(
          (const __attribute__((address_space(1))) void*)gb,
          (__attribute__((address_space(3))) void*)lb, 16, 0, 0);
    }
    __syncthreads();
    bf16x8 av[4], bv[4];
    #pragma unroll
    for (int mi = 0; mi < 4; ++mi)
      av[mi] = *(const bf16x8*)(Apan + ((size_t)(kb / 8 + qk) * 64 + mi * 16 + lm) * 8);
    #pragma unroll
    for (int ni = 0; ni < 4; ++ni)
      bv[ni] = *(const bf16x8*)(Bt + (size_t)(wave * 64 + ni * 16 + lm) * 32 + qk * 8);
    #pragma unroll
    for (int mi = 0; mi < 4; ++mi)
      #pragma unroll
      for (int ni = 0; ni < 4; ++ni)
        acc[mi][ni] = __builtin_amdgcn_mfma_f32_16x16x32_bf16(
            bv[ni], av[mi], acc[mi][ni], 0, 0, 0);  // swapped operands
    __syncthreads();
  }

  // ---- epilogue: row = bm + mi*16 + lm, cols = bn + wave*64 + ni*16 + qk*4 ----
  #pragma unroll
  for (int ni = 0; ni < 4; ++ni) {
    int colg = bn + wave * 64 + ni * 16 + qk * 4;
    float4 b4 = {0.f, 0.f, 0.f, 0.f};
    if (BIAS) b4 = *(const float4*)&bias[colg];
    #pragma unroll
    for (int mi = 0; mi < 4; ++mi) {
      int rowg = bm + mi * 16 + lm;
      float v0 = acc[mi][ni][0] + b4.x;
      float v1 = acc[mi][ni][1] + b4.y;
      float v2 = acc[mi][ni][2] + b4.z;
      float v3 = acc[mi][ni][3] + b4.w;
      if (RELU) {
        v0 = fmaxf(v0, 0.f); v1 = fmaxf(v1, 0.f);
        v2 = fmaxf(v2, 0.f); v3 = fmaxf(v3, 0.f);
      }
      if (SPLITOUT) {
        if (colg < 256) {
          ushort4 o = {f2bf(v0), f2bf(v1), f2bf(v2), f2bf(v3)};
          *(ushort4*)&Cb[(size_t)rowg * 256 + colg] = o;
        } else {
          float4 o = {v0, v1, v2, v3};
          *(float4*)&Cf[(size_t)rowg * 256 + (colg - 256)] = o;
        }
      } else if (OUT_BF16) {
        ushort4 o = {f2bf(v0), f2bf(v1), f2bf(v2), f2bf(v3)};
        *(ushort4*)&Cb[(size_t)rowg * 512 + colg] = o;
      } else {
        float4 o = {v0, v1, v2, v3};
        *(float4*)&Cf[(size_t)rowg * 512 + colg] = o;
      }
    }
  }
}

extern "C" void kernel_launch(void* const* d_in, const int* in_sizes, int n_in,
                              void* d_out, int out_size, void* d_ws, size_t ws_size,
                              hipStream_t stream) {
  const float* x = (const float*)d_in[0];
  const int* ei = (const int*)d_in[1];  // int32 per harness, [2][E]
  const float* W1l = (const float*)d_in[2];
  const float* b1 = (const float*)d_in[3];
  const float* W1r = (const float*)d_in[4];
  const float* W2l = (const float*)d_in[5];
  const float* b2 = (const float*)d_in[6];
  const float* W2r = (const float*)d_in[7];
  float* out = (float*)d_out;

  char* ws = (char*)d_ws;
  size_t off = 0;
  auto alloc = [&](size_t bytes) {
    void* p = ws + off;
    off = (off + bytes + 255) & ~(size_t)255;
    return p;
  };
  int* deg = (int*)alloc((size_t)N_NODES * 4);
  int* rowptr = (int*)alloc((size_t)(N_NODES + 1) * 4);
  int* cursor = (int*)alloc((size_t)N_NODES * 4);
  int* col = (int*)alloc((size_t)N_EDGES * 4);
  int* bsum = (int*)alloc((size_t)NB_SCAN * 4);
  int* boff = (int*)alloc((size_t)NB_SCAN * 4);
  ushort_t* x_bf = (ushort_t*)alloc((size_t)N_NODES * F_IN * 2);
  ushort_t* aggx_bf = (ushort_t*)alloc((size_t)N_NODES * F_IN * 2);
  ushort_t* h_bf = (ushort_t*)alloc((size_t)N_NODES * F_HID * 2);
  ushort_t* hl_bf = (ushort_t*)alloc((size_t)N_NODES * F_OUT * 2);  // h@W2l, bf16
  float* hr = (float*)alloc((size_t)N_NODES * F_OUT * 4);           // h@W2r + b2
  ushort_t* Wcat1t = (ushort_t*)alloc((size_t)512 * 256 * 2);  // [512 n][W1l^T|W1r^T]
  ushort_t* Wcatt = (ushort_t*)alloc((size_t)512 * F_HID * 2); // [512 n][512 k]
  float* biascat = (float*)alloc(512 * 4);

  // CSR build
  hipMemsetAsync(deg, 0, (size_t)N_NODES * 4, stream);
  deg_kernel<<<(N_EDGES + 255) / 256, 256, 0, stream>>>(ei, deg);
  scanA_kernel<<<NB_SCAN, 256, 0, stream>>>(deg, bsum);
  scanB_kernel<<<1, 256, 0, stream>>>(bsum, boff);
  scanC_kernel<<<NB_SCAN, 256, 0, stream>>>(deg, boff, rowptr, cursor);
  fill_kernel<<<(N_EDGES + 255) / 256, 256, 0, stream>>>(ei, cursor, col);

  // Conversions (independent of CSR)
  cvt_x_kernel<<<(N_NODES * F_IN / 4 + 255) / 256, 256, 0, stream>>>(x, x_bf);
  wt_kernel<<<(F_IN * F_HID + 255) / 256, 256, 0, stream>>>(W1l, Wcat1t, 128, 512, 0, 0, 256);
  wt_kernel<<<(F_IN * F_HID + 255) / 256, 256, 0, stream>>>(W1r, Wcat1t, 128, 512, 0, 128, 256);
  wt_kernel<<<(F_HID * F_OUT + 255) / 256, 256, 0, stream>>>(W2l, Wcatt, 512, 256, 0, 0, 512);
  wt_kernel<<<(F_HID * F_OUT + 255) / 256, 256, 0, stream>>>(W2r, Wcatt, 512, 256, 256, 0, 512);
  biascat_kernel<<<2, 256, 0, stream>>>(b2, biascat);

  // Layer 1: aggx_bf = mean-agg(x_bf); h_bf = relu([aggx|x] @ [W1l;W1r] + b1)
  agg1_kernel<<<N_NODES, 64, 0, stream>>>(x_bf, aggx_bf, rowptr, col);
  gemm_mfma<true, true, true, true, false, 256>
      <<<dim3(2, N_NODES / 64), 256, 0, stream>>>(
          aggx_bf, x_bf, Wcat1t, b1, nullptr, h_bf, N_NODES);

  // Layer 2 fused: [hl_bf | hr] = h_bf @ [W2l|W2r] + [0|b2], split outputs
  gemm_mfma<false, false, true, false, true, 512>
      <<<dim3(2, N_NODES / 64), 256, 0, stream>>>(
          h_bf, nullptr, Wcatt, biascat, hr, hl_bf, N_NODES);
  // out = mean-agg(hl_bf) + hr
  agg2_kernel<<<N_NODES, 128, 0, stream>>>(hl_bf, hr, out, rowptr, col);
}